// Round 2
// baseline (629.403 us; speedup 1.0000x reference)
//
#include <hip/hip_runtime.h>

typedef unsigned short u16;
typedef unsigned int u32;
typedef __attribute__((ext_vector_type(8))) __bf16 bf16x8;
typedef __attribute__((ext_vector_type(16))) float f32x16;

#define NN 8192
#define IND 512
#define DD 256
#define SPL 4
#define JCHUNK 2048
// ln(1 + 2^-9): folded into exp so that bf16-truncation of P is unbiased
#define LN_K 0.00195122595f

__device__ __forceinline__ void gl_lds16(const void* g, void* l) {
  __builtin_amdgcn_global_load_lds((const __attribute__((address_space(1))) void*)g,
                                   (__attribute__((address_space(3))) void*)l, 16, 0, 0);
}
__device__ __forceinline__ u16 bf16_rne(float x) {
  u32 u = __float_as_uint(x);
  u += 0x7FFF + ((u >> 16) & 1);
  return (u16)(u >> 16);
}

// ---------------- kernel 0a: W fp32 [512,256] -> WT bf16 [256,512], x3 -----
__global__ __launch_bounds__(256) void wt_transpose(const float* __restrict__ Wq,
                                                    const float* __restrict__ Wk,
                                                    const float* __restrict__ Wv,
                                                    u16* __restrict__ WT) {
  const int o = blockIdx.y;
  const int e = blockIdx.x * 256 + threadIdx.x;  // < 131072
  const int n = e >> 9, k = e & 511;             // WT[n][k] <- W[k][n]
  const float* W = (o == 0) ? Wq : ((o == 1) ? Wk : Wv);
  WT[o * (DD * IND) + e] = bf16_rne(W[k * DD + n]);
}

// ---------------- kernel 0b: feat fp32 [8192,512] -> bf16 ------------------
__global__ __launch_bounds__(256) void cvt_feat(const float* __restrict__ f,
                                                u16* __restrict__ fb) {
  const int i = (blockIdx.x * 256 + threadIdx.x) * 4;  // 4M elems / 4
  float4 v = *(const float4*)(f + i);
  u32 lo = (u32)bf16_rne(v.x) | ((u32)bf16_rne(v.y) << 16);
  u32 hi = (u32)bf16_rne(v.z) | ((u32)bf16_rne(v.w) << 16);
  *(uint2*)(fb + i) = make_uint2(lo, hi);
}

// ---------------- kernel 1: projections Q/16, K (row-major), VT ------------
__global__ __launch_bounds__(256, 2) void proj_qkv(const u16* __restrict__ featb,
                                                   const u16* __restrict__ WT,
                                                   u16* __restrict__ Qs,
                                                   u16* __restrict__ Ks,
                                                   u16* __restrict__ VTs) {
  __shared__ u16 tl[4][32 * 40];  // per-wave transpose buffer, pitch 40 keeps 16B align
  const int mb = blockIdx.x, o = blockIdx.y;
  const int wave = threadIdx.x >> 6, lane = threadIdx.x & 63;
  const int mm = lane & 31, h = lane >> 5;
  const int m0 = mb * 128 + wave * 32;
  const u16* wt = WT + o * (DD * IND);

  f32x16 acc[8];
#pragma unroll
  for (int nt = 0; nt < 8; ++nt)
#pragma unroll
    for (int r = 0; r < 16; ++r) acc[nt][r] = 0.f;

  for (int kc = 0; kc < 32; ++kc) {
    bf16x8 af = *(const bf16x8*)(featb + (size_t)(m0 + mm) * IND + kc * 16 + 8 * h);
#pragma unroll
    for (int nt = 0; nt < 8; ++nt) {
      bf16x8 bf = *(const bf16x8*)(wt + (size_t)(nt * 32 + mm) * IND + kc * 16 + 8 * h);
      acc[nt] = __builtin_amdgcn_mfma_f32_32x32x16_bf16(af, bf, acc[nt], 0, 0, 0);
    }
  }

  if (o < 2) {
    const float sc = (o == 0) ? 0.0625f : 1.f;  // fold 1/sqrt(256) into Q
    u16* dst = (o == 0) ? Qs : Ks;
#pragma unroll
    for (int nt = 0; nt < 8; ++nt)
#pragma unroll
      for (int r = 0; r < 16; ++r) {
        const int mrow = (r & 3) + 8 * (r >> 2) + 4 * h;
        dst[(size_t)(m0 + mrow) * DD + nt * 32 + mm] = bf16_rne(acc[nt][r] * sc);
      }
  } else {
    // V -> VT via per-wave LDS transpose, coalesced 32B stores per lane
    const int n2 = lane >> 1, mh = lane & 1;
    for (int nt = 0; nt < 8; ++nt) {
#pragma unroll
      for (int r = 0; r < 16; r += 2) {
        const int mrow = (r & 3) + 8 * (r >> 2) + 4 * h;  // even; pair (r,r+1)->(m,m+1)
        u32 pk = (u32)bf16_rne(acc[nt][r]) | ((u32)bf16_rne(acc[nt][r + 1]) << 16);
        *(u32*)(&tl[wave][mm * 40 + mrow]) = pk;
      }
      __syncthreads();  // writes visible (block-uniform loop; all waves same count)
      bf16x8 t0 = *(const bf16x8*)(&tl[wave][n2 * 40 + mh * 16]);
      bf16x8 t1 = *(const bf16x8*)(&tl[wave][n2 * 40 + mh * 16 + 8]);
      u16* gp = VTs + (size_t)(nt * 32 + n2) * NN + m0 + mh * 16;
      *(bf16x8*)(gp) = t0;
      *(bf16x8*)(gp + 8) = t1;
      __syncthreads();  // reads done before next nt overwrites
    }
  }
}

// ---------------- kernel 2: fused flash attention with counting weights ----
// wave = 32 Q-rows; S^T = K.Q^T (32x32x16 MFMA); O' = V^T.P ; j-split SPL ways
__global__ __launch_bounds__(256, 2) void flash_attn(const u16* __restrict__ Qs,
                                                     const u16* __restrict__ Ks,
                                                     const u16* __restrict__ VTs,
                                                     const float* __restrict__ cnt,
                                                     float* __restrict__ ml,
                                                     float* __restrict__ Op) {
  __shared__ u16 kl[8192];  // K chunk, 16B-block layout (kb*32 + j)
  __shared__ u16 vl[8192];  // VT chunk, 16B-block layout (jb*256 + n)
  const int rb = blockIdx.x, sp = blockIdx.y;
  const int wave = threadIdx.x >> 6, lane = threadIdx.x & 63;
  const int mm = lane & 31, h = lane >> 5;
  const int m0 = rb * 128 + wave * 32;

  // persistent Q fragments: B-operand, lane holds Q[m0+mm][kc*16 + 8h .. +7]
  bf16x8 qf[16];
  {
    const u16* qrow = Qs + (size_t)(m0 + mm) * DD;
#pragma unroll
    for (int c = 0; c < 16; ++c) qf[c] = *(const bf16x8*)(qrow + c * 16 + 8 * h);
  }
  f32x16 acc[8];
#pragma unroll
  for (int nt = 0; nt < 8; ++nt)
#pragma unroll
    for (int r = 0; r < 16; ++r) acc[nt][r] = 0.f;
  float m_run = -1e30f, l_run = 0.f;

  int j0 = sp * JCHUNK;
  for (int jb = 0; jb < JCHUNK / 32; ++jb, j0 += 32) {
    __syncthreads();  // previous iter's LDS readers done
#pragma unroll
    for (int ii = 0; ii < 4; ++ii) {
      const int w = wave * 4 + ii;
      const int L = w * 64 + lane;
      // K: LDS block index = kb*32 + j  (kb = k/8)
      gl_lds16(Ks + (size_t)(j0 + (L & 31)) * DD + (L >> 5) * 8, (char*)kl + w * 1024);
      // V: LDS block index = jb*256 + n (jb = jlocal/8), from VT rows
      gl_lds16(VTs + (size_t)(L & 255) * NN + j0 + (L >> 8) * 8, (char*)vl + w * 1024);
    }
    // counting_attn (fp32) for this lane's 16 jj slots: jj(r) = (r&3)+8*(r>>2)+4h
    float cf[16];
    {
      const float* crow = cnt + (size_t)(m0 + mm) * NN + j0 + 4 * h;
#pragma unroll
      for (int g = 0; g < 4; ++g) {
        float4 t = *(const float4*)(crow + 8 * g);
        cf[4 * g + 0] = t.x;
        cf[4 * g + 1] = t.y;
        cf[4 * g + 2] = t.z;
        cf[4 * g + 3] = t.w;
      }
    }
    __syncthreads();  // staging complete

    // S^T accumulate, two chains for ILP
    f32x16 sv0, sv1;
#pragma unroll
    for (int r = 0; r < 16; ++r) { sv0[r] = 0.f; sv1[r] = 0.f; }
#pragma unroll
    for (int c = 0; c < 16; c += 2) {
      bf16x8 kf0 = *(const bf16x8*)((const char*)kl + (((2 * c + h) * 32 + mm) << 4));
      bf16x8 kf1 = *(const bf16x8*)((const char*)kl + (((2 * c + 2 + h) * 32 + mm) << 4));
      sv0 = __builtin_amdgcn_mfma_f32_32x32x16_bf16(kf0, qf[c], sv0, 0, 0, 0);
      sv1 = __builtin_amdgcn_mfma_f32_32x32x16_bf16(kf1, qf[c + 1], sv1, 0, 0, 0);
    }
    f32x16 sv = sv0 + sv1;

    // online softmax: per-lane state indexed by mm = lane&31 (q-row)
    float mx = sv[0];
#pragma unroll
    for (int r = 1; r < 16; ++r) mx = fmaxf(mx, sv[r]);
    mx = fmaxf(mx, __shfl_xor(mx, 32));
    const float m_new = fmaxf(m_run, mx);
    const bool upd = __any(mx > m_run);
    const float msub = m_new - LN_K;

    float p[16];
    float bsum = 0.f;
#pragma unroll
    for (int r = 0; r < 16; ++r) {
      p[r] = __expf(sv[r] - msub) * cf[r];
      bsum += p[r];
    }
    bsum += __shfl_xor(bsum, 32);

    if (upd) {
      const float alpha = __expf(m_run - m_new);
      l_run = l_run * alpha + bsum;
#pragma unroll
      for (int nt = 0; nt < 8; ++nt)
#pragma unroll
        for (int r = 0; r < 16; ++r) acc[nt][r] *= alpha;
    } else {
      l_run += bsum;
    }
    m_run = m_new;

    // pack P pairs (bf16 trunc; bias cancelled by LN_K scale)
    u32 P2[8];
#pragma unroll
    for (int j = 0; j < 8; ++j) {
      const u32 ua = __float_as_uint(p[2 * j]);
      const u32 ub = __float_as_uint(p[2 * j + 1]);
      P2[j] = (ua >> 16) | (ub & 0xFFFF0000u);
    }
    // PV: O'[n][mm] += V^T[n][jj] * P[jj][mm]
#pragma unroll
    for (int kc2 = 0; kc2 < 2; ++kc2) {
      union { u32 u[4]; bf16x8 v; } pf;
#pragma unroll
      for (int tp = 0; tp < 4; ++tp) {
        const int src = mm + 32 * (tp >> 1);
        const u32 va = __shfl(P2[4 * kc2 + (tp & 1)], src);
        const u32 vb = __shfl(P2[4 * kc2 + 2 + (tp & 1)], src);
        pf.u[tp] = h ? vb : va;
      }
#pragma unroll
      for (int nt = 0; nt < 8; ++nt) {
        bf16x8 vf = *(const bf16x8*)((const char*)vl +
                                     ((((2 * kc2 + h) * 256) + nt * 32 + mm) << 4));
        acc[nt] = __builtin_amdgcn_mfma_f32_32x32x16_bf16(vf, pf.v, acc[nt], 0, 0, 0);
      }
    }
  }

  // partials
  const int wb = rb * 4 + wave;
  if (lane < 32) {
    ml[((sp * 256 + wb) << 6) + lane] = m_run;
    ml[((sp * 256 + wb) << 6) + 32 + lane] = l_run;
  }
#pragma unroll
  for (int nt = 0; nt < 8; ++nt) {
    float* obase = Op + ((((size_t)(sp * 256 + wb) * 8 + nt) * 64 + lane) << 4);
#pragma unroll
    for (int rr = 0; rr < 4; ++rr) {
      float4 v = make_float4(acc[nt][4 * rr], acc[nt][4 * rr + 1],
                             acc[nt][4 * rr + 2], acc[nt][4 * rr + 3]);
      *(float4*)(obase + 4 * rr) = v;
    }
  }
}

// ---------------- kernel 3: merge splits + elu + fp32 out ------------------
__global__ __launch_bounds__(256) void merge_out(const float* __restrict__ ml,
                                                 const float* __restrict__ Op,
                                                 float* __restrict__ out) {
  const int wid = blockIdx.x * 4 + (threadIdx.x >> 6);
  const int lane = threadIdx.x & 63, mm = lane & 31, h = lane >> 5;
  const int wb = wid >> 3, nt = wid & 7;
  float mv[SPL], lv[SPL], wsc[SPL];
#pragma unroll
  for (int s = 0; s < SPL; ++s) {
    mv[s] = ml[((s * 256 + wb) << 6) + mm];
    lv[s] = ml[((s * 256 + wb) << 6) + 32 + mm];
  }
  float M = mv[0];
#pragma unroll
  for (int s = 1; s < SPL; ++s) M = fmaxf(M, mv[s]);
  float L = 0.f;
#pragma unroll
  for (int s = 0; s < SPL; ++s) {
    wsc[s] = __expf(mv[s] - M);
    L += wsc[s] * lv[s];
  }
  const float inv = 1.f / (L + 1e-9f);

  float o[16];
#pragma unroll
  for (int r = 0; r < 16; ++r) o[r] = 0.f;
#pragma unroll
  for (int s = 0; s < SPL; ++s) {
    const float* ob = Op + ((((size_t)(s * 256 + wb) * 8 + nt) * 64 + lane) << 4);
#pragma unroll
    for (int rr = 0; rr < 4; ++rr) {
      float4 v = *(const float4*)(ob + 4 * rr);
      o[4 * rr + 0] += wsc[s] * v.x;
      o[4 * rr + 1] += wsc[s] * v.y;
      o[4 * rr + 2] += wsc[s] * v.z;
      o[4 * rr + 3] += wsc[s] * v.w;
    }
  }
  // out[row][col], col = (r&3) + 8*(r>>2) + 4h: contiguous float4 per g=r>>2
  const int row = wb * 32 + mm;
#pragma unroll
  for (int g = 0; g < 4; ++g) {
    float4 v;
    float* pv = &v.x;
#pragma unroll
    for (int i = 0; i < 4; ++i) {
      float t = o[4 * g + i] * inv;
      pv[i] = t > 0.f ? t : expm1f(t);  // elu, alpha=1
    }
    *(float4*)(out + (size_t)row * DD + nt * 32 + 8 * g + 4 * h) = v;
  }
}

extern "C" void kernel_launch(void* const* d_in, const int* in_sizes, int n_in,
                              void* d_out, int out_size, void* d_ws, size_t ws_size,
                              hipStream_t stream) {
  const float* feat = (const float*)d_in[0];
  const float* cnta = (const float*)d_in[1];
  const float* Wq = (const float*)d_in[2];
  const float* Wk = (const float*)d_in[3];
  const float* Wv = (const float*)d_in[4];
  char* ws = (char*)d_ws;
  u16* WT = (u16*)(ws);                      // 768 KB
  u16* featb = (u16*)(ws + (1ull << 20));    // 8 MB
  u16* Qs = (u16*)(ws + (9ull << 20));       // 4 MB
  u16* Ks = (u16*)(ws + (13ull << 20));      // 4 MB
  u16* VTs = (u16*)(ws + (17ull << 20));     // 4 MB
  float* ml = (float*)(ws + (21ull << 20));  // 256 KB
  float* Op = (float*)(ws + (22ull << 20));  // 32 MB  (total 54 MB)
  float* out = (float*)d_out;

  hipLaunchKernelGGL(wt_transpose, dim3(512, 3), dim3(256), 0, stream, Wq, Wk, Wv, WT);
  hipLaunchKernelGGL(cvt_feat, dim3(4096), dim3(256), 0, stream, feat, featb);
  hipLaunchKernelGGL(proj_qkv, dim3(64, 3), dim3(256), 0, stream, featb, WT, Qs, Ks, VTs);
  hipLaunchKernelGGL(flash_attn, dim3(64, SPL), dim3(256), 0, stream, Qs, Ks, VTs, cnta, ml, Op);
  hipLaunchKernelGGL(merge_out, dim3(512), dim3(256), 0, stream, ml, Op, out);
}

// Round 3
// 578.216 us; speedup vs baseline: 1.0885x; 1.0885x over previous
//
#include <hip/hip_runtime.h>

typedef unsigned short u16;
typedef unsigned int u32;
typedef __attribute__((ext_vector_type(8))) __bf16 bf16x8;
typedef __attribute__((ext_vector_type(16))) float f32x16;

#define NN 8192
#define IND 512
#define DD 256
// ln(1 + 2^-9): folded into exp so that bf16-truncation of P is unbiased
#define LN_K 0.00195122595f

__device__ __forceinline__ void gl_lds16(const void* g, void* l) {
  __builtin_amdgcn_global_load_lds((const __attribute__((address_space(1))) void*)g,
                                   (__attribute__((address_space(3))) void*)l, 16, 0, 0);
}
__device__ __forceinline__ u16 bf16_rne(float x) {
  u32 u = __float_as_uint(x);
  u += 0x7FFF + ((u >> 16) & 1);
  return (u16)(u >> 16);
}

// ---------------- kernel 0a: W fp32 [512,256] -> WT bf16 [256,512], x3 -----
__global__ __launch_bounds__(256) void wt_transpose(const float* __restrict__ Wq,
                                                    const float* __restrict__ Wk,
                                                    const float* __restrict__ Wv,
                                                    u16* __restrict__ WT) {
  const int o = blockIdx.y;
  const int e = blockIdx.x * 256 + threadIdx.x;  // < 131072
  const int n = e >> 9, k = e & 511;             // WT[n][k] <- W[k][n]
  const float* W = (o == 0) ? Wq : ((o == 1) ? Wk : Wv);
  WT[o * (DD * IND) + e] = bf16_rne(W[k * DD + n]);
}

// ---------------- kernel 0b: feat fp32 [8192,512] -> bf16 ------------------
__global__ __launch_bounds__(256) void cvt_feat(const float* __restrict__ f,
                                                u16* __restrict__ fb) {
  const int i = (blockIdx.x * 256 + threadIdx.x) * 4;  // 4M elems / 4
  float4 v = *(const float4*)(f + i);
  u32 lo = (u32)bf16_rne(v.x) | ((u32)bf16_rne(v.y) << 16);
  u32 hi = (u32)bf16_rne(v.z) | ((u32)bf16_rne(v.w) << 16);
  *(uint2*)(fb + i) = make_uint2(lo, hi);
}

// ---------------- kernel 1: projections Q/16, K (row-major), VT ------------
__global__ __launch_bounds__(256, 2) void proj_qkv(const u16* __restrict__ featb,
                                                   const u16* __restrict__ WT,
                                                   u16* __restrict__ Qs,
                                                   u16* __restrict__ Ks,
                                                   u16* __restrict__ VTs) {
  __shared__ u16 tl[4][32 * 40];  // per-wave transpose buffer, pitch 40 keeps 16B align
  const int mb = blockIdx.x, o = blockIdx.y;
  const int wave = threadIdx.x >> 6, lane = threadIdx.x & 63;
  const int mm = lane & 31, h = lane >> 5;
  const int m0 = mb * 128 + wave * 32;
  const u16* wt = WT + o * (DD * IND);

  f32x16 acc[8];
#pragma unroll
  for (int nt = 0; nt < 8; ++nt)
#pragma unroll
    for (int r = 0; r < 16; ++r) acc[nt][r] = 0.f;

  for (int kc = 0; kc < 32; ++kc) {
    bf16x8 af = *(const bf16x8*)(featb + (size_t)(m0 + mm) * IND + kc * 16 + 8 * h);
#pragma unroll
    for (int nt = 0; nt < 8; ++nt) {
      bf16x8 bf = *(const bf16x8*)(wt + (size_t)(nt * 32 + mm) * IND + kc * 16 + 8 * h);
      acc[nt] = __builtin_amdgcn_mfma_f32_32x32x16_bf16(af, bf, acc[nt], 0, 0, 0);
    }
  }

  if (o < 2) {
    const float sc = (o == 0) ? 0.0625f : 1.f;  // fold 1/sqrt(256) into Q
    u16* dst = (o == 0) ? Qs : Ks;
#pragma unroll
    for (int nt = 0; nt < 8; ++nt)
#pragma unroll
      for (int r = 0; r < 16; ++r) {
        const int mrow = (r & 3) + 8 * (r >> 2) + 4 * h;
        dst[(size_t)(m0 + mrow) * DD + nt * 32 + mm] = bf16_rne(acc[nt][r] * sc);
      }
  } else {
    // V -> VT via per-wave LDS transpose, coalesced 32B stores per lane
    const int n2 = lane >> 1, mh = lane & 1;
    for (int nt = 0; nt < 8; ++nt) {
#pragma unroll
      for (int r = 0; r < 16; r += 2) {
        const int mrow = (r & 3) + 8 * (r >> 2) + 4 * h;  // even; pair (r,r+1)->(m,m+1)
        u32 pk = (u32)bf16_rne(acc[nt][r]) | ((u32)bf16_rne(acc[nt][r + 1]) << 16);
        *(u32*)(&tl[wave][mm * 40 + mrow]) = pk;
      }
      __syncthreads();  // writes visible (block-uniform loop; all waves same count)
      bf16x8 t0 = *(const bf16x8*)(&tl[wave][n2 * 40 + mh * 16]);
      bf16x8 t1 = *(const bf16x8*)(&tl[wave][n2 * 40 + mh * 16 + 8]);
      u16* gp = VTs + (size_t)(nt * 32 + n2) * NN + m0 + mh * 16;
      *(bf16x8*)(gp) = t0;
      *(bf16x8*)(gp + 8) = t1;
      __syncthreads();  // reads done before next nt overwrites
    }
  }
}

// ---------------- kernel 2: fused flash attention, double-buffered ---------
// wave = 32 Q-rows; S^T = K.Q^T (32x32x16 MFMA); O' = V^T.P ; j-split spl ways
// LDS: 2x(16KB K + 16KB V); single barrier per iter, a full compute-phase
// after the next chunk's global_load_lds issue -> drain is cheap.
__global__ __launch_bounds__(256, 2) void flash_attn(const u16* __restrict__ Qs,
                                                     const u16* __restrict__ Ks,
                                                     const u16* __restrict__ VTs,
                                                     const float* __restrict__ cnt,
                                                     float* __restrict__ ml,
                                                     float* __restrict__ Op,
                                                     int jiters) {
  __shared__ u16 kl[2][8192];  // K chunk, 16B-block layout (kb*32 + j)
  __shared__ u16 vl[2][8192];  // VT chunk, 16B-block layout (jb*256 + n)
  const int rb = blockIdx.x, sp = blockIdx.y;
  const int wave = threadIdx.x >> 6, lane = threadIdx.x & 63;
  const int mm = lane & 31, h = lane >> 5;
  const int m0 = rb * 128 + wave * 32;
  const int jbase = sp * jiters * 32;

  // staging addresses (lane-invariant decomposition of L = w*64+lane)
  const int Lw = lane;  // combined with w below

  // persistent Q fragments: B-operand, lane holds Q[m0+mm][kc*16 + 8h .. +7]
  bf16x8 qf[16];
  {
    const u16* qrow = Qs + (size_t)(m0 + mm) * DD;
#pragma unroll
    for (int c = 0; c < 16; ++c) qf[c] = *(const bf16x8*)(qrow + c * 16 + 8 * h);
  }
  f32x16 acc[8];
#pragma unroll
  for (int nt = 0; nt < 8; ++nt)
#pragma unroll
    for (int r = 0; r < 16; ++r) acc[nt][r] = 0.f;
  float m_run = -1e30f, l_run = 0.f;

  // prologue: stage chunk 0 into buffer 0
#pragma unroll
  for (int ii = 0; ii < 4; ++ii) {
    const int w = wave * 4 + ii;
    const int L = w * 64 + Lw;
    gl_lds16(Ks + (size_t)(jbase + (L & 31)) * DD + (L >> 5) * 8, (char*)kl + w * 1024);
    gl_lds16(VTs + (size_t)(L & 255) * NN + jbase + (L >> 8) * 8, (char*)vl + w * 1024);
  }
  __syncthreads();

  for (int jb = 0; jb < jiters; ++jb) {
    const int buf = jb & 1;
    const int j0 = jbase + jb * 32;
    // stage NEXT chunk into the other buffer (block-uniform guard)
    if (jb + 1 < jiters) {
      const int jn = j0 + 32;
#pragma unroll
      for (int ii = 0; ii < 4; ++ii) {
        const int w = wave * 4 + ii;
        const int L = w * 64 + Lw;
        gl_lds16(Ks + (size_t)(jn + (L & 31)) * DD + (L >> 5) * 8,
                 (char*)kl + (buf ^ 1) * 16384 + w * 1024);
        gl_lds16(VTs + (size_t)(L & 255) * NN + jn + (L >> 8) * 8,
                 (char*)vl + (buf ^ 1) * 16384 + w * 1024);
      }
    }
    // counting_attn (fp32) for this lane's 16 jj slots: jj(r) = (r&3)+8*(r>>2)+4h
    float cf[16];
    {
      const float* crow = cnt + (size_t)(m0 + mm) * NN + j0 + 4 * h;
#pragma unroll
      for (int g = 0; g < 4; ++g) {
        float4 t = *(const float4*)(crow + 8 * g);
        cf[4 * g + 0] = t.x;
        cf[4 * g + 1] = t.y;
        cf[4 * g + 2] = t.z;
        cf[4 * g + 3] = t.w;
      }
    }

    // S^T accumulate from current buffer, two chains for ILP
    const char* klb = (const char*)kl + buf * 16384;
    const char* vlb = (const char*)vl + buf * 16384;
    f32x16 sv0, sv1;
#pragma unroll
    for (int r = 0; r < 16; ++r) { sv0[r] = 0.f; sv1[r] = 0.f; }
#pragma unroll
    for (int c = 0; c < 16; c += 2) {
      bf16x8 kf0 = *(const bf16x8*)(klb + (((2 * c + h) * 32 + mm) << 4));
      bf16x8 kf1 = *(const bf16x8*)(klb + (((2 * c + 2 + h) * 32 + mm) << 4));
      sv0 = __builtin_amdgcn_mfma_f32_32x32x16_bf16(kf0, qf[c], sv0, 0, 0, 0);
      sv1 = __builtin_amdgcn_mfma_f32_32x32x16_bf16(kf1, qf[c + 1], sv1, 0, 0, 0);
    }
    f32x16 sv = sv0 + sv1;

    // online softmax: per-lane state indexed by mm = lane&31 (q-row)
    float mx = sv[0];
#pragma unroll
    for (int r = 1; r < 16; ++r) mx = fmaxf(mx, sv[r]);
    mx = fmaxf(mx, __shfl_xor(mx, 32));
    const float m_new = fmaxf(m_run, mx);
    const bool upd = __any(mx > m_run);
    const float msub = m_new - LN_K;

    float p[16];
    float bsum = 0.f;
#pragma unroll
    for (int r = 0; r < 16; ++r) {
      p[r] = __expf(sv[r] - msub) * cf[r];
      bsum += p[r];
    }
    bsum += __shfl_xor(bsum, 32);

    if (upd) {
      const float alpha = __expf(m_run - m_new);
      l_run = l_run * alpha + bsum;
#pragma unroll
      for (int nt = 0; nt < 8; ++nt)
#pragma unroll
        for (int r = 0; r < 16; ++r) acc[nt][r] *= alpha;
    } else {
      l_run += bsum;
    }
    m_run = m_new;

    // pack P pairs (bf16 trunc; bias cancelled by LN_K scale)
    u32 P2[8];
#pragma unroll
    for (int j = 0; j < 8; ++j) {
      const u32 ua = __float_as_uint(p[2 * j]);
      const u32 ub = __float_as_uint(p[2 * j + 1]);
      P2[j] = (ua >> 16) | (ub & 0xFFFF0000u);
    }
    // PV: O'[n][mm] += V^T[n][jj] * P[jj][mm]
#pragma unroll
    for (int kc2 = 0; kc2 < 2; ++kc2) {
      union { u32 u[4]; bf16x8 v; } pf;
#pragma unroll
      for (int tp = 0; tp < 4; ++tp) {
        const int src = mm + 32 * (tp >> 1);
        const u32 va = __shfl(P2[4 * kc2 + (tp & 1)], src);
        const u32 vb = __shfl(P2[4 * kc2 + 2 + (tp & 1)], src);
        pf.u[tp] = h ? vb : va;
      }
#pragma unroll
      for (int nt = 0; nt < 8; ++nt) {
        bf16x8 vf = *(const bf16x8*)(vlb + ((((2 * kc2 + h) * 256) + nt * 32 + mm) << 4));
        acc[nt] = __builtin_amdgcn_mfma_f32_32x32x16_bf16(vf, pf.v, acc[nt], 0, 0, 0);
      }
    }
    __syncthreads();  // drains next-chunk stage (issued ~full iter ago); guards reuse
  }

  // partials
  const int wb = rb * 4 + wave;
  if (lane < 32) {
    ml[((sp * 256 + wb) << 6) + lane] = m_run;
    ml[((sp * 256 + wb) << 6) + 32 + lane] = l_run;
  }
#pragma unroll
  for (int nt = 0; nt < 8; ++nt) {
#pragma unroll
    for (int rr = 0; rr < 4; ++rr) {
      // lane-major: wave stores 1KB contiguous per (nt,rr)
      float* op = Op + ((((size_t)(sp * 256 + wb) * 8 + nt) * 4 + rr) * 64 + lane) * 4;
      float4 v = make_float4(acc[nt][4 * rr], acc[nt][4 * rr + 1],
                             acc[nt][4 * rr + 2], acc[nt][4 * rr + 3]);
      *(float4*)op = v;
    }
  }
}

// ---------------- kernel 3: merge splits + elu + fp32 out ------------------
__global__ __launch_bounds__(256) void merge_out(const float* __restrict__ ml,
                                                 const float* __restrict__ Op,
                                                 float* __restrict__ out,
                                                 int spl) {
  const int wid = blockIdx.x * 4 + (threadIdx.x >> 6);
  const int lane = threadIdx.x & 63, mm = lane & 31, h = lane >> 5;
  const int wb = wid >> 3, nt = wid & 7;
  float mv[8], lv[8], wsc[8];
  for (int s = 0; s < spl; ++s) {
    mv[s] = ml[((s * 256 + wb) << 6) + mm];
    lv[s] = ml[((s * 256 + wb) << 6) + 32 + mm];
  }
  float M = mv[0];
  for (int s = 1; s < spl; ++s) M = fmaxf(M, mv[s]);
  float L = 0.f;
  for (int s = 0; s < spl; ++s) {
    wsc[s] = __expf(mv[s] - M);
    L += wsc[s] * lv[s];
  }
  const float inv = 1.f / (L + 1e-9f);

  float o[16];
#pragma unroll
  for (int r = 0; r < 16; ++r) o[r] = 0.f;
  for (int s = 0; s < spl; ++s) {
#pragma unroll
    for (int rr = 0; rr < 4; ++rr) {
      const float* op = Op + ((((size_t)(s * 256 + wb) * 8 + nt) * 4 + rr) * 64 + lane) * 4;
      float4 v = *(const float4*)op;
      o[4 * rr + 0] += wsc[s] * v.x;
      o[4 * rr + 1] += wsc[s] * v.y;
      o[4 * rr + 2] += wsc[s] * v.z;
      o[4 * rr + 3] += wsc[s] * v.w;
    }
  }
  // out[row][col], col = (r&3) + 8*(r>>2) + 4h: contiguous float4 per g=r>>2
  const int row = wb * 32 + mm;
#pragma unroll
  for (int g = 0; g < 4; ++g) {
    float4 v;
    float* pv = &v.x;
#pragma unroll
    for (int i = 0; i < 4; ++i) {
      float t = o[4 * g + i] * inv;
      pv[i] = t > 0.f ? t : expm1f(t);  // elu, alpha=1
    }
    *(float4*)(out + (size_t)row * DD + nt * 32 + 8 * g + 4 * h) = v;
  }
}

extern "C" void kernel_launch(void* const* d_in, const int* in_sizes, int n_in,
                              void* d_out, int out_size, void* d_ws, size_t ws_size,
                              hipStream_t stream) {
  const float* feat = (const float*)d_in[0];
  const float* cnta = (const float*)d_in[1];
  const float* Wq = (const float*)d_in[2];
  const float* Wk = (const float*)d_in[3];
  const float* Wv = (const float*)d_in[4];
  char* ws = (char*)d_ws;
  u16* WT = (u16*)(ws);                      // 768 KB
  u16* featb = (u16*)(ws + (1ull << 20));    // 8 MB
  u16* Qs = (u16*)(ws + (9ull << 20));       // 4 MB
  u16* Ks = (u16*)(ws + (13ull << 20));      // 4 MB
  u16* VTs = (u16*)(ws + (17ull << 20));     // 4 MB
  float* ml = (float*)(ws + (21ull << 20));  // 1 MB (spl<=8)
  float* Op = (float*)(ws + (22ull << 20));  // spl*8 MB
  float* out = (float*)d_out;

  // spl=8 needs 22MB + 64MB = 86MB of ws; fall back to proven 54MB layout.
  const size_t need8 = (22ull << 20) + (64ull << 20);
  const int spl = (ws_size >= need8) ? 8 : 4;
  const int jiters = NN / (spl * 32);

  hipLaunchKernelGGL(wt_transpose, dim3(512, 3), dim3(256), 0, stream, Wq, Wk, Wv, WT);
  hipLaunchKernelGGL(cvt_feat, dim3(4096), dim3(256), 0, stream, feat, featb);
  hipLaunchKernelGGL(proj_qkv, dim3(64, 3), dim3(256), 0, stream, featb, WT, Qs, Ks, VTs);
  hipLaunchKernelGGL(flash_attn, dim3(64, spl), dim3(256), 0, stream, Qs, Ks, VTs, cnta, ml, Op,
                     jiters);
  hipLaunchKernelGGL(merge_out, dim3(512), dim3(256), 0, stream, ml, Op, out, spl);
}